// Round 2
// baseline (147.727 us; speedup 1.0000x reference)
//
#include <hip/hip_runtime.h>

typedef unsigned short ushort_t;
typedef __attribute__((ext_vector_type(8))) short short8;   // 8 bf16 in 4 VGPRs
typedef __attribute__((ext_vector_type(4))) float f32x4;
typedef __attribute__((ext_vector_type(16))) float f32x16;
typedef __attribute__((ext_vector_type(2))) unsigned int uint2v;
typedef __attribute__((ext_vector_type(4))) unsigned int uint4v;
typedef __attribute__((ext_vector_type(2))) unsigned int uint2s;

typedef __attribute__((address_space(1))) const unsigned char gaddr_t;
typedef __attribute__((address_space(3))) unsigned char laddr_t;

__device__ __forceinline__ unsigned short f2bf(float x) {
  unsigned u = __float_as_uint(x);
  u += 0x7FFF + ((u >> 16) & 1);     // round-to-nearest-even
  return (unsigned short)(u >> 16);
}
__device__ __forceinline__ float bf2f(unsigned short u) {
  return __uint_as_float(((unsigned)u) << 16);
}
__device__ __forceinline__ unsigned cvt_pk_bf16(float lo, float hi) {
  unsigned r;
  asm("v_cvt_pk_bf16_f32 %0, %1, %2" : "=v"(r) : "v"(lo), "v"(hi));
  return r;
}

__device__ __forceinline__ void gl_lds16(const void* g, void* l) {
  __builtin_amdgcn_global_load_lds((gaddr_t*)g, (laddr_t*)l, 16, 0, 0);
}

// active-tile recurrence (identical FP ops everywhere -> identical masks)
__device__ __forceinline__ unsigned active_mask(const float* __restrict__ tb) {
  unsigned am = 0;
  float run = -INFINITY;
#pragma unroll
  for (int tt = 0; tt < 32; tt++) {
    float tm = tb[tt];
    if (tm > run - 40.f) am |= (1u << tt);
    run = fmaxf(run, tm);
  }
  return am;
}

// ---------------- prep0: mask prescale + per-tile maxima (must precede consumers) ----------------
__global__ void prep0(const float* __restrict__ maskin, float* __restrict__ maskpre,
                      float* __restrict__ tmaxbuf) {
  const float CM = -1.442695041e9f;    // -1e9 * log2(e)
  int bx = blockIdx.x;
  if (bx < 8) {
    int i = bx * 1024 + threadIdx.x * 4;
    f32x4 v = *(const f32x4*)(maskin + i);
    v *= CM;
    *(f32x4*)(maskpre + i) = v;
  } else {
    int t = threadIdx.x;
    if (t < 128) {
      const float* src = maskin + (t >> 5) * 2048 + (t & 31) * 64;
      float mn = src[0];
#pragma unroll
      for (int j = 1; j < 64; j++) mn = fminf(mn, src[j]);
      tmaxbuf[t] = mn * CM;   // CM < 0: max of prescaled = CM * min(raw)
    }
  }
}

// ---------------- prep1: cvt(QKV, tile-sparse for K/V) + wtrans(4) ----------------
__global__ void prep1(const float4* __restrict__ q4, const float4* __restrict__ k4,
                      const float4* __restrict__ v4,
                      ushort4* __restrict__ xq, ushort4* __restrict__ xk,
                      ushort4* __restrict__ xv,
                      const float* __restrict__ W0, const float* __restrict__ W1,
                      const float* __restrict__ W2, const float* __restrict__ W3,
                      ushort_t* __restrict__ T0, ushort_t* __restrict__ T1,
                      ushort_t* __restrict__ T2, ushort_t* __restrict__ T3,
                      const float* __restrict__ tmaxbuf) {
  const int K = 1024, N = 1024;
  __shared__ ushort_t tile[32][33];
  int bx = blockIdx.x;
  if (bx < 3072) {
    int z = bx >> 10, bl = bx & 1023;           // block covers rows [bl*8, bl*8+8)
    if (z > 0) {
      int b = bl >> 8, tl = (bl >> 3) & 31;
      unsigned am = active_mask(tmaxbuf + b * 32);
      if (!((am >> tl) & 1u)) return;
    }
    const float4* in = (z == 0) ? q4 : (z == 1) ? k4 : v4;
    ushort4* out = (z == 0) ? xq : (z == 1) ? xk : xv;
    const float4* src = in + (long)bl * 2048;
    ushort4* dst = out + (long)bl * 2048;
    int t = threadIdx.x;
#pragma unroll
    for (int j = 0; j < 8; j++) {
      int idx = j * 256 + t;
      float4 v = src[idx];
      ushort4 o;
      o.x = f2bf(v.x); o.y = f2bf(v.y); o.z = f2bf(v.z); o.w = f2bf(v.w);
      dst[idx] = o;
    }
  } else {
    int idx = bx - 3072;
    int z = idx >> 10;
    const float* W = (z == 0) ? W0 : (z == 1) ? W1 : (z == 2) ? W2 : W3;
    ushort_t* Wt = (z == 0) ? T0 : (z == 1) ? T1 : (z == 2) ? T2 : T3;
    int n0 = (idx & 31) * 32, k0 = ((idx >> 5) & 31) * 32;
    int tx = threadIdx.x & 31, ty = threadIdx.x >> 5;  // 32 x 8
#pragma unroll
    for (int r = 0; r < 4; r++) {
      int k = k0 + ty + r * 8;
      tile[ty + r * 8][tx] = f2bf(W[(long)k * N + n0 + tx]);
    }
    __syncthreads();
#pragma unroll
    for (int r = 0; r < 4; r++) {
      int n = n0 + ty + r * 8;
      Wt[(long)n * K + k0 + tx] = tile[tx][ty + r * 8];
    }
  }
}

// ---------------- batched QKV GEMM: 256x256 tile, 8 waves, BK=32, 4-buf prefetch-3 ----------------
// One resident generation (~240 blocks); 2 waves/SIMD from a single block.
// z==2 (V) writes Vt[B,H,64,S] directly via per-wave LDS transpose.
__global__ __launch_bounds__(512, 2) void gemm_qkv3(
    const ushort_t* __restrict__ Aq, const ushort_t* __restrict__ Ak, const ushort_t* __restrict__ Av,
    const ushort_t* __restrict__ Bq, const ushort_t* __restrict__ Bk, const ushort_t* __restrict__ Bv,
    const float* __restrict__ bq, const float* __restrict__ bk, const float* __restrict__ bv,
    ushort_t* __restrict__ Cq, ushort_t* __restrict__ Ck, ushort_t* __restrict__ Vt,
    const float* __restrict__ tmaxbuf) {
  const int K = 1024, N = 1024;
  const int z = blockIdx.y;
  const ushort_t* A = z == 0 ? Aq : z == 1 ? Ak : Av;
  const ushort_t* Bt = z == 0 ? Bq : z == 1 ? Bk : Bv;
  const float* bias = z == 0 ? bq : z == 1 ? bk : bv;

  __shared__ __align__(16) char smem[131072];   // 4 bufs x (A 16KB | B 16KB)
  const int t = threadIdx.x, w = t >> 6, l = t & 63;

  // XCD-chunked: m_idx = (i&3)*8 + xcd -> A-panel's 4 n-blocks share an XCD,
  // consecutive m round-robin across XCDs (balances K/V activity clustering).
  const int orig = blockIdx.x;                   // 0..127
  const int xcd = orig & 7, i = orig >> 3;       // i in 0..15
  const int m0 = ((i & 3) * 8 + xcd) * 256;
  const int n0 = (i >> 2) * 256;
  const int wr = (w >> 2) * 128, wc = (w & 3) * 64;   // per-wave 128x64 output

  if (z != 0) {
    // rows [m0, m0+256) = 4 tiles of 64 within batch m0>>11
    int b_ = m0 >> 11, tile0 = (m0 & 2047) >> 6;
    unsigned am = active_mask(tmaxbuf + b_ * 32);
    if (!((am >> tile0) & 15u)) return;
  }

  f32x4 acc[8][4] = {};

  const int br0 = w * 32 + (l >> 2);                   // staged row (call 0)
  const int bcs = ((l & 3) ^ ((l >> 3) & 3)) << 3;     // inverse-swizzled ushort col
  const ushort_t* Ab = A + (long)m0 * K;
  const ushort_t* Bb = Bt + (long)n0 * K;

  auto stage = [&](int kk, int buf) {
    char* base = smem + buf * 32768;
    gl_lds16(Ab + (long)br0 * K + kk + bcs, base + w * 2048);
    gl_lds16(Ab + (long)(br0 + 16) * K + kk + bcs, base + w * 2048 + 1024);
    gl_lds16(Bb + (long)br0 * K + kk + bcs, base + 16384 + w * 2048);
    gl_lds16(Bb + (long)(br0 + 16) * K + kk + bcs, base + 16384 + w * 2048 + 1024);
  };

  stage(0, 0);
  stage(32, 1);
  stage(64, 2);

  // fragment-read byte offsets (swizzled 16B chunk)
  const int fsw = ((l >> 4) ^ ((l >> 1) & 3)) << 4;
  const int arow = (wr + (l & 15)) * 64 + fsw;           // A: + m*1024 per m-frag
  const int brow = 16384 + (wc + (l & 15)) * 64 + fsw;   // B: + n*1024 per n-frag

  asm volatile("s_waitcnt vmcnt(8)");                    // stage(0) landed
  __builtin_amdgcn_sched_barrier(0);
  __builtin_amdgcn_s_barrier();

  for (int ts = 0; ts < 32; ts++) {
    const char* base = smem + (ts & 3) * 32768;
    if (ts + 3 < 32) stage((ts + 3) * 32, (ts + 3) & 3); // overwrites buf read at ts-1
    short8 af[8], bfr[4];
#pragma unroll
    for (int m = 0; m < 8; m++)
      af[m] = *(const short8*)(base + arow + m * 1024);
#pragma unroll
    for (int n = 0; n < 4; n++)
      bfr[n] = *(const short8*)(base + brow + n * 1024);
    __builtin_amdgcn_s_setprio(1);
#pragma unroll
    for (int m = 0; m < 8; m++)
#pragma unroll
      for (int n = 0; n < 4; n++)
        acc[m][n] = __builtin_amdgcn_mfma_f32_16x16x32_bf16(af[m], bfr[n], acc[m][n], 0, 0, 0);
    __builtin_amdgcn_s_setprio(0);
    // counted wait: stage(ts+1) complete; up to 8 loads (2 stages) stay in flight.
    if (ts < 29) asm volatile("s_waitcnt vmcnt(8)");
    else if (ts == 29) asm volatile("s_waitcnt vmcnt(4)");
    else if (ts == 30) asm volatile("s_waitcnt vmcnt(0)");
    if (ts < 31) {
      __builtin_amdgcn_sched_barrier(0);
      __builtin_amdgcn_s_barrier();
    }
  }
  __builtin_amdgcn_s_barrier();   // all reads consumed; LDS free for epilogue reuse

  // ---- epilogue via per-wave LDS transpose (16 KB/wave) ----
  char* Lw = smem + w * 16384;
  if (z != 2) {
#pragma unroll
    for (int nn = 0; nn < 4; nn++) {
      float bvv = bias[n0 + wc + nn * 16 + (l & 15)];
      int dl = nn * 16 + (l & 15);
#pragma unroll
      for (int mm = 0; mm < 8; mm++)
#pragma unroll
        for (int i2 = 0; i2 < 4; i2++) {
          int sl = mm * 16 + (l >> 4) * 4 + i2;
          *(ushort_t*)(Lw + sl * 128 + ((dl * 2) ^ ((sl & 7) << 4))) =
              f2bf(acc[mm][nn][i2] + bvv);
        }
    }
    ushort_t* C = (z == 0 ? Cq : Ck) + (long)(m0 + wr) * N + n0 + wc;
#pragma unroll
    for (int rr = 0; rr < 16; rr++) {
      int sl = rr * 8 + (l >> 3);
      short8 vv = *(const short8*)(Lw + sl * 128 + (((l & 7) * 16) ^ ((sl & 7) << 4)));
      *(short8*)(C + (long)sl * N + (l & 7) * 8) = vv;
    }
  } else {
    // Vt transpose: wave tile [dl 0..64)[s 0..128), 256B rows, XOR-swizzled
#pragma unroll
    for (int nn = 0; nn < 4; nn++) {
      float bvv = bias[n0 + wc + nn * 16 + (l & 15)];
      int dl = nn * 16 + (l & 15);
#pragma unroll
      for (int mm = 0; mm < 8; mm++) {
        int sl = mm * 16 + (l >> 4) * 4;
        uint2s pk;
        pk.x = cvt_pk_bf16(acc[mm][nn][0] + bvv, acc[mm][nn][1] + bvv);
        pk.y = cvt_pk_bf16(acc[mm][nn][2] + bvv, acc[mm][nn][3] + bvv);
        *(uint2s*)(Lw + dl * 256 + ((sl * 2) ^ ((dl & 7) << 4))) = pk;
      }
    }
    const int b_ = m0 >> 11;
    const int s0g = (m0 & 2047) + wr;
#pragma unroll
    for (int rr = 0; rr < 8; rr++) {
      int dl = rr * 8 + (l >> 3);
      int dg = n0 + wc + dl;
      long rowbase = ((long)(b_ * 16 + (dg >> 6)) * 64 + (dg & 63)) * 2048;
#pragma unroll
      for (int sh = 0; sh < 2; sh++) {
        int c = (l & 7) + sh * 8;
        short8 vv = *(const short8*)(Lw + dl * 256 + ((c * 16) ^ ((dl & 7) << 4)));
        *(short8*)(Vt + rowbase + s0g + c * 8) = vv;
      }
    }
  }
}

// ---------------- output projection GEMM: 256x256, 8 waves, BK=32, 4-buf prefetch-3 ----------------
__global__ __launch_bounds__(512, 2) void gemm_o(const ushort_t* __restrict__ A,
                                                 const ushort_t* __restrict__ Bt,
                                                 const float* __restrict__ bias,
                                                 float* __restrict__ C) {
  const int K = 1024, N = 1024;
  __shared__ __align__(16) char smem[131072];
  const int t = threadIdx.x, w = t >> 6, l = t & 63;

  const int orig = blockIdx.x;                   // 0..127
  const int xcd = orig & 7, i = orig >> 3;
  const int m0 = ((i & 3) * 8 + xcd) * 256;
  const int n0 = (i >> 2) * 256;
  const int wr = (w >> 2) * 128, wc = (w & 3) * 64;

  f32x4 acc[8][4] = {};

  const int br0 = w * 32 + (l >> 2);
  const int bcs = ((l & 3) ^ ((l >> 3) & 3)) << 3;
  const ushort_t* Ab = A + (long)m0 * K;
  const ushort_t* Bb = Bt + (long)n0 * K;

  auto stage = [&](int kk, int buf) {
    char* base = smem + buf * 32768;
    gl_lds16(Ab + (long)br0 * K + kk + bcs, base + w * 2048);
    gl_lds16(Ab + (long)(br0 + 16) * K + kk + bcs, base + w * 2048 + 1024);
    gl_lds16(Bb + (long)br0 * K + kk + bcs, base + 16384 + w * 2048);
    gl_lds16(Bb + (long)(br0 + 16) * K + kk + bcs, base + 16384 + w * 2048 + 1024);
  };

  stage(0, 0);
  stage(32, 1);
  stage(64, 2);

  const int fsw = ((l >> 4) ^ ((l >> 1) & 3)) << 4;
  const int arow = (wr + (l & 15)) * 64 + fsw;
  const int brow = 16384 + (wc + (l & 15)) * 64 + fsw;

  asm volatile("s_waitcnt vmcnt(8)");
  __builtin_amdgcn_sched_barrier(0);
  __builtin_amdgcn_s_barrier();

  for (int ts = 0; ts < 32; ts++) {
    const char* base = smem + (ts & 3) * 32768;
    if (ts + 3 < 32) stage((ts + 3) * 32, (ts + 3) & 3);
    short8 af[8], bfr[4];
#pragma unroll
    for (int m = 0; m < 8; m++)
      af[m] = *(const short8*)(base + arow + m * 1024);
#pragma unroll
    for (int n = 0; n < 4; n++)
      bfr[n] = *(const short8*)(base + brow + n * 1024);
    __builtin_amdgcn_s_setprio(1);
#pragma unroll
    for (int m = 0; m < 8; m++)
#pragma unroll
      for (int n = 0; n < 4; n++)
        acc[m][n] = __builtin_amdgcn_mfma_f32_16x16x32_bf16(af[m], bfr[n], acc[m][n], 0, 0, 0);
    __builtin_amdgcn_s_setprio(0);
    if (ts < 29) asm volatile("s_waitcnt vmcnt(8)");
    else if (ts == 29) asm volatile("s_waitcnt vmcnt(4)");
    else if (ts == 30) asm volatile("s_waitcnt vmcnt(0)");
    if (ts < 31) {
      __builtin_amdgcn_sched_barrier(0);
      __builtin_amdgcn_s_barrier();
    }
  }

#pragma unroll
  for (int mm = 0; mm < 8; mm++)
#pragma unroll
    for (int nn = 0; nn < 4; nn++) {
      int c = n0 + wc + nn * 16 + (l & 15);
      float bv = bias[c];
#pragma unroll
      for (int i2 = 0; i2 < 4; i2++) {
        int r = m0 + wr + mm * 16 + (l >> 4) * 4 + i2;
        C[(long)r * N + c] = acc[mm][nn][i2] + bv;
      }
    }
}

// ---------------- flash attention (swapped 32x32, block-sparse via mask tile-max) ----------------
__global__ __launch_bounds__(256, 4) void attn(
    const ushort_t* __restrict__ Qp, const ushort_t* __restrict__ Kp,
    const ushort_t* __restrict__ Vt, const float* __restrict__ maskpre,
    const float* __restrict__ tmaxbuf, ushort_t* __restrict__ Ob) {
  const int S = 2048, DM = 1024;
  __shared__ __align__(16) char smem[32768];
  char* KlB = smem;                 // 2 x 8192
  char* VlB = smem + 16384;         // 2 x 8192

  const int t = threadIdx.x, w = t >> 6, l = t & 63;
  const int lq = l & 31, hi = l >> 5;
  const int hib = hi * 16;

  const int orig = blockIdx.x + (blockIdx.y << 4) + (blockIdx.z << 8);
  const int work = ((orig & 7) << 7) + (orig >> 3);
  const int qx = work & 15;
  const int hb = work >> 4;          // [0,64)
  const int h = hb & 15, b = hb >> 4;
  const int q0w = qx * 128 + w * 32;

  const float C1 = 0.1803368801f;      // 0.125 * log2(e)

  const ushort_t* Kbase = Kp + (long)(b * S) * DM + h * 64;
  const ushort_t* Vbase = Vt + (long)((b * 16 + h) * 64) * S;
  const float* Mbase = maskpre + (long)b * S;

  short8 qB[4];
  {
    const ushort_t* Qb = Qp + ((long)(b * S) + q0w + lq) * DM + h * 64;
#pragma unroll
    for (int kh = 0; kh < 4; kh++)
      qB[kh] = *(const short8*)(Qb + kh * 16 + hi * 8);
  }

  const int so0 = w * 2048 + l * 16;
  const int sr0 = so0 >> 7, sc0 = (so0 & 127) ^ ((sr0 & 7) << 4);
  const int so1 = so0 + 1024;
  const int sr1 = so1 >> 7, sc1 = (so1 & 127) ^ ((sr1 & 7) << 4);
  const ushort_t* Kg0 = Kbase + (long)sr0 * DM + (sc0 >> 1);
  const ushort_t* Kg1 = Kbase + (long)sr1 * DM + (sc1 >> 1);
  const ushort_t* Vg0 = Vbase + (long)sr0 * S + (sc0 >> 1);
  const ushort_t* Vg1 = Vbase + (long)sr1 * S + (sc1 >> 1);
  char* Kd0 = KlB + w * 2048;
  char* Vd0 = VlB + w * 2048;

  auto stage = [&](int kv0, int bb) {
    long ko = (long)kv0 * DM;
    int bo = bb * 8192;
    gl_lds16(Kg0 + ko, Kd0 + bo);
    gl_lds16(Kg1 + ko, Kd0 + bo + 1024);
    gl_lds16(Vg0 + kv0, Vd0 + bo);
    gl_lds16(Vg1 + kv0, Vd0 + bo + 1024);
  };

  unsigned amask = active_mask(tmaxbuf + b * 32);

  int cur = (int)__builtin_ctz(amask);   // bit 0 always set
  stage(cur * 64, 0);
  __syncthreads();

  const int lbase = lq * 128 + ((lq & 7) << 4);   // row lq base ^ swizzle (bytes)

  f32x16 o0 = {}, o1 = {};           // O^T: row d (0..31 / 32..63), col q=lq
  float mrun = -INFINITY, lsum = 0.f;
  int bb = 0;

  while (cur >= 0) {
    unsigned rem = amask & (0xFFFFFFFEu << cur);
    int nxt = rem ? (int)__builtin_ctz(rem) : -1;
    if (nxt >= 0) stage(nxt * 64, bb ^ 1);
    const int bx = lbase + (bb << 13);
    const int kv0 = cur * 64;

    f32x16 s0 = {}, s1 = {};
    __builtin_amdgcn_s_setprio(1);
#pragma unroll
    for (int kh = 0; kh < 4; kh++) {
      int a = bx ^ (kh * 32 + hib);
      short8 ka0 = *(const short8*)(KlB + a);
      short8 ka1 = *(const short8*)(KlB + a + 4096);
      s0 = __builtin_amdgcn_mfma_f32_32x32x16_bf16(ka0, qB[kh], s0, 0, 0, 0);
      s1 = __builtin_amdgcn_mfma_f32_32x32x16_bf16(ka1, qB[kh], s1, 0, 0, 0);
    }
    __builtin_amdgcn_s_setprio(0);

    const float* mq = Mbase + kv0;
#pragma unroll
    for (int g = 0; g < 4; g++) {
      f32x4 m0 = *(const f32x4*)(mq + g * 8 + hi * 4);
      f32x4 m1 = *(const f32x4*)(mq + 32 + g * 8 + hi * 4);
#pragma unroll
      for (int c = 0; c < 4; c++) {
        s0[g * 4 + c] = fmaf(s0[g * 4 + c], C1, m0[c]);
        s1[g * 4 + c] = fmaf(s1[g * 4 + c], C1, m1[c]);
      }
    }

    float mx0 = -INFINITY, mx1 = -INFINITY, mx2 = -INFINITY, mx3 = -INFINITY;
#pragma unroll
    for (int r = 0; r < 4; r++) {
      mx0 = fmaxf(mx0, fmaxf(s0[r], s0[r + 4]));
      mx1 = fmaxf(mx1, fmaxf(s0[r + 8], s0[r + 12]));
      mx2 = fmaxf(mx2, fmaxf(s1[r], s1[r + 4]));
      mx3 = fmaxf(mx3, fmaxf(s1[r + 8], s1[r + 12]));
    }
    float mx = fmaxf(fmaxf(mx0, mx1), fmaxf(mx2, mx3));
    mx = fmaxf(mx, __shfl_xor(mx, 32));

    if (!__all((int)(mx <= mrun + 8.f))) {
      float mnew = fmaxf(mrun, mx);
      float sc = __builtin_amdgcn_exp2f(mrun - mnew);
      mrun = mnew;
      lsum *= sc;
#pragma unroll
      for (int r = 0; r < 16; r++) { o0[r] *= sc; o1[r] *= sc; }
    }

    float ps0 = 0.f, ps1 = 0.f, ps2 = 0.f, ps3 = 0.f;
#pragma unroll
    for (int r = 0; r < 8; r++) {
      float p0 = __builtin_amdgcn_exp2f(s0[r] - mrun);
      float p1 = __builtin_amdgcn_exp2f(s0[r + 8] - mrun);
      float p2 = __builtin_amdgcn_exp2f(s1[r] - mrun);
      float p3 = __builtin_amdgcn_exp2f(s1[r + 8] - mrun);
      s0[r] = p0; s0[r + 8] = p1; s1[r] = p2; s1[r + 8] = p3;
      ps0 += p0; ps1 += p1; ps2 += p2; ps3 += p3;
    }
    float ps = (ps0 + ps1) + (ps2 + ps3);
    ps += __shfl_xor(ps, 32);
    lsum += ps;

    // ---- PV: P repacked in-register via v_cvt_pk + permlane32_swap (T12) ----
#pragma unroll
    for (int half = 0; half < 2; half++) {
      const f32x16& sv = half ? s1 : s0;
      unsigned x0 = cvt_pk_bf16(sv[0], sv[1]);
      unsigned z0 = cvt_pk_bf16(sv[2], sv[3]);
      unsigned y0 = cvt_pk_bf16(sv[4], sv[5]);
      unsigned u0 = cvt_pk_bf16(sv[6], sv[7]);
      unsigned x1 = cvt_pk_bf16(sv[8], sv[9]);
      unsigned z1 = cvt_pk_bf16(sv[10], sv[11]);
      unsigned y1 = cvt_pk_bf16(sv[12], sv[13]);
      unsigned u1 = cvt_pk_bf16(sv[14], sv[15]);
      uint2v a1 = __builtin_amdgcn_permlane32_swap(x0, y0, false, false);
      uint2v a2 = __builtin_amdgcn_permlane32_swap(z0, u0, false, false);
      uint2v a3 = __builtin_amdgcn_permlane32_swap(x1, y1, false, false);
      uint2v a4 = __builtin_amdgcn_permlane32_swap(z1, u1, false, false);
      uint4v f0, f1;
      f0.x = a1.x; f0.y = a2.x; f0.z = a1.y; f0.w = a2.y;
      f1.x = a3.x; f1.y = a4.x; f1.z = a3.y; f1.w = a4.y;
      short8 pB0 = __builtin_bit_cast(short8, f0);
      short8 pB1 = __builtin_bit_cast(short8, f1);
      __builtin_amdgcn_s_setprio(1);
#pragma unroll
      for (int kt2 = 0; kt2 < 2; kt2++) {
        short8 pB = kt2 ? pB1 : pB0;
        int a = bx ^ (half * 64 + kt2 * 32 + hib);
        short8 va0 = *(const short8*)(VlB + a);
        short8 va1 = *(const short8*)(VlB + a + 4096);
        o0 = __builtin_amdgcn_mfma_f32_32x32x16_bf16(va0, pB, o0, 0, 0, 0);
        o1 = __builtin_amdgcn_mfma_f32_32x32x16_bf16(va1, pB, o1, 0, 0, 0);
      }
      __builtin_amdgcn_s_setprio(0);
    }
    __syncthreads();
    bb ^= 1;
    cur = nxt;
  }

  __syncthreads();
  char* Ow = smem + w * 4096;        // [32 q][64 d] bf16, XOR-swizzled rows
  float inv = 1.0f / lsum;
#pragma unroll
  for (int r = 0; r < 16; r++) {
    int d0 = (r & 3) + 8 * (r >> 2) + 4 * hi;
    int a0 = lq * 128 + ((d0 * 2) ^ ((lq & 7) << 4));
    *(ushort_t*)(Ow + a0) = f2bf(o0[r] * inv);
    int d1 = 32 + d0;
    int a1 = lq * 128 + ((d1 * 2) ^ ((lq & 7) << 4));
    *(ushort_t*)(Ow + a1) = f2bf(o1[r] * inv);
  }
  ushort_t* Obase = Ob + ((long)(b * S) + q0w) * DM + h * 64;
#pragma unroll
  for (int rr = 0; rr < 4; rr++) {
    int q = rr * 8 + (l >> 3);
    int a = q * 128 + (((l & 7) * 16) ^ ((q & 7) << 4));
    short8 vv = *(const short8*)(Ow + a);
    *(short8*)(Obase + (long)q * DM + (l & 7) * 8) = vv;
  }
}

// ---------------- launch ----------------
extern "C" void kernel_launch(void* const* d_in, const int* in_sizes, int n_in,
                              void* d_out, int out_size, void* d_ws, size_t ws_size,
                              hipStream_t stream) {
  const float* query = (const float*)d_in[0];
  const float* key   = (const float*)d_in[1];
  const float* value = (const float*)d_in[2];
  const float* mask  = (const float*)d_in[3];
  const float* Wq = (const float*)d_in[4];
  const float* bq = (const float*)d_in[5];
  const float* Wk = (const float*)d_in[6];
  const float* bk = (const float*)d_in[7];
  const float* Wv = (const float*)d_in[8];
  const float* bv = (const float*)d_in[9];
  const float* Wo = (const float*)d_in[10];
  const float* bo = (const float*)d_in[11];

  const int B = 4, S = 2048, DM = 1024, H = 16;
  const long M = (long)B * S;            // 8192
  const long XB = (long)1 << 24;         // 16 MiB bf16 activation bytes

  char* ws = (char*)d_ws;
  ushort_t* Wqt = (ushort_t*)(ws);
  ushort_t* Wkt = (ushort_t*)(ws + (1l << 21));
  ushort_t* Wvt = (ushort_t*)(ws + 2 * (1l << 21));
  ushort_t* Wot = (ushort_t*)(ws + 3 * (1l << 21));
  ushort_t* Xv  = (ushort_t*)(ws + 4 * (1l << 21));
  ushort_t* Qp  = (ushort_t*)(ws + 4 * (1l << 21) + XB);
  ushort_t* Kp  = Qp + M * DM;
  ushort_t* Vtr = Kp + M * DM;           // Vt[B,H,64,S] (Vp never materialized)
  float* maskpre = (float*)(Vtr + M * DM);
  float* tmaxbuf = maskpre + (long)B * S;
  ushort_t* AO  = Xv;                    // Xv dead after V projection
  ushort_t* Xq  = (ushort_t*)d_out;      // d_out holds 2 bf16 scratch arrays
  ushort_t* Xk  = Xq + M * DM;

  prep0<<<9, 256, 0, stream>>>(mask, maskpre, tmaxbuf);

  prep1<<<7168, 256, 0, stream>>>((const float4*)query, (const float4*)key,
                                  (const float4*)value, (ushort4*)Xq, (ushort4*)Xk,
                                  (ushort4*)Xv, Wq, Wk, Wv, Wo, Wqt, Wkt, Wvt, Wot,
                                  tmaxbuf);

  gemm_qkv3<<<dim3(128, 3), 512, 0, stream>>>(Xq, Xk, Xv, Wqt, Wkt, Wvt,
                                              bq, bk, bv, Qp, Kp, Vtr, tmaxbuf);

  attn<<<dim3(16, 16, 4), 256, 0, stream>>>(Qp, Kp, Vtr, maskpre, tmaxbuf, AO);

  gemm_o<<<128, 512, 0, stream>>>(AO, Wot, bo, (float*)d_out);
}

// Round 7
// 130.234 us; speedup vs baseline: 1.1343x; 1.1343x over previous
//
#include <hip/hip_runtime.h>

typedef unsigned short ushort_t;
typedef __attribute__((ext_vector_type(8))) short short8;   // 8 bf16 in 4 VGPRs
typedef __attribute__((ext_vector_type(4))) float f32x4;
typedef __attribute__((ext_vector_type(16))) float f32x16;
typedef __attribute__((ext_vector_type(2))) unsigned int uint2v;
typedef __attribute__((ext_vector_type(4))) unsigned int uint4v;
typedef __attribute__((ext_vector_type(2))) unsigned int uint2s;

typedef __attribute__((address_space(1))) const unsigned char gaddr_t;
typedef __attribute__((address_space(3))) unsigned char laddr_t;

__device__ __forceinline__ unsigned short f2bf(float x) {
  unsigned u = __float_as_uint(x);
  u += 0x7FFF + ((u >> 16) & 1);     // round-to-nearest-even
  return (unsigned short)(u >> 16);
}
__device__ __forceinline__ float bf2f(unsigned short u) {
  return __uint_as_float(((unsigned)u) << 16);
}
__device__ __forceinline__ unsigned cvt_pk_bf16(float lo, float hi) {
  unsigned r;
  asm("v_cvt_pk_bf16_f32 %0, %1, %2" : "=v"(r) : "v"(lo), "v"(hi));
  return r;
}

__device__ __forceinline__ void gl_lds16(const void* g, void* l) {
  __builtin_amdgcn_global_load_lds((gaddr_t*)g, (laddr_t*)l, 16, 0, 0);
}

// active-tile recurrence (identical FP ops everywhere -> identical masks)
__device__ __forceinline__ unsigned active_mask(const float* __restrict__ tb) {
  unsigned am = 0;
  float run = -INFINITY;
#pragma unroll
  for (int tt = 0; tt < 32; tt++) {
    float tm = tb[tt];
    if (tm > run - 40.f) am |= (1u << tt);
    run = fmaxf(run, tm);
  }
  return am;
}

// ---------------- prep0: mask prescale + per-tile maxima (must precede consumers) ----------------
// blocks [0,8): maskpre = mask * CM; block 8: tilemax
__global__ void prep0(const float* __restrict__ maskin, float* __restrict__ maskpre,
                      float* __restrict__ tmaxbuf) {
  const float CM = -1.442695041e9f;    // -1e9 * log2(e)
  int bx = blockIdx.x;
  if (bx < 8) {
    int i = bx * 1024 + threadIdx.x * 4;
    f32x4 v = *(const f32x4*)(maskin + i);
    v *= CM;
    *(f32x4*)(maskpre + i) = v;
  } else {
    int t = threadIdx.x;
    if (t < 128) {
      const float* src = maskin + (t >> 5) * 2048 + (t & 31) * 64;
      float mn = src[0];
#pragma unroll
      for (int j = 1; j < 64; j++) mn = fminf(mn, src[j]);
      tmaxbuf[t] = mn * CM;   // CM < 0: max of prescaled = CM * min(raw)
    }
  }
}

// ---------------- prep1: cvt(QKV, tile-sparse for K/V) + wtrans(4) ----------------
// blocks [0,3072): cvt (block bl covers 8 rows); [3072,7168): wtrans
__global__ void prep1(const float4* __restrict__ q4, const float4* __restrict__ k4,
                      const float4* __restrict__ v4,
                      ushort4* __restrict__ xq, ushort4* __restrict__ xk,
                      ushort4* __restrict__ xv,
                      const float* __restrict__ W0, const float* __restrict__ W1,
                      const float* __restrict__ W2, const float* __restrict__ W3,
                      ushort_t* __restrict__ T0, ushort_t* __restrict__ T1,
                      ushort_t* __restrict__ T2, ushort_t* __restrict__ T3,
                      const float* __restrict__ tmaxbuf) {
  const int K = 1024, N = 1024;
  __shared__ ushort_t tile[32][33];
  int bx = blockIdx.x;
  if (bx < 3072) {
    int z = bx >> 10, bl = bx & 1023;           // block covers rows [bl*8, bl*8+8)
    if (z > 0) {
      // K/V: skip rows whose 64-row tile is inactive (outputs provably unread)
      int b = bl >> 8, tl = (bl >> 3) & 31;
      unsigned am = active_mask(tmaxbuf + b * 32);
      if (!((am >> tl) & 1u)) return;
    }
    const float4* in = (z == 0) ? q4 : (z == 1) ? k4 : v4;
    ushort4* out = (z == 0) ? xq : (z == 1) ? xk : xv;
    const float4* src = in + (long)bl * 2048;
    ushort4* dst = out + (long)bl * 2048;
    int t = threadIdx.x;
#pragma unroll
    for (int j = 0; j < 8; j++) {
      int idx = j * 256 + t;
      float4 v = src[idx];
      ushort4 o;
      o.x = f2bf(v.x); o.y = f2bf(v.y); o.z = f2bf(v.z); o.w = f2bf(v.w);
      dst[idx] = o;
    }
  } else {
    int idx = bx - 3072;
    int z = idx >> 10;
    const float* W = (z == 0) ? W0 : (z == 1) ? W1 : (z == 2) ? W2 : W3;
    ushort_t* Wt = (z == 0) ? T0 : (z == 1) ? T1 : (z == 2) ? T2 : T3;
    int n0 = (idx & 31) * 32, k0 = ((idx >> 5) & 31) * 32;
    int tx = threadIdx.x & 31, ty = threadIdx.x >> 5;  // 32 x 8
#pragma unroll
    for (int r = 0; r < 4; r++) {
      int k = k0 + ty + r * 8;
      tile[ty + r * 8][tx] = f2bf(W[(long)k * N + n0 + tx]);
    }
    __syncthreads();
#pragma unroll
    for (int r = 0; r < 4; r++) {
      int n = n0 + ty + r * 8;
      Wt[(long)n * K + k0 + tx] = tile[tx][ty + r * 8];
    }
  }
}

// ---------------- batched QKV GEMM: bf16 A, gl_lds, 3-buf counted-vmcnt pipeline ----------------
// z==0 (Q): full. z==1/2 (K/V): m-blocks with both 64-row tiles inactive exit early.
// z==2 (V) writes Vt[B,H,64,S] directly; epilogues via per-wave LDS transpose.
// LDS tiles XOR-swizzled (chunk ^= (row>>1)&3 at 16B granularity): inverse swizzle
// applied to the global SOURCE of global_load_lds (dest stays linear), same XOR on
// fragment reads -> row-stride-64B 8-way bank conflict becomes 2-way (free).
// NOTE: stage call 1 covers tile rows [64,128): br0 + 64 (round-6 regression was +16).
__global__ void gemm_qkv3(
    const ushort_t* __restrict__ Aq, const ushort_t* __restrict__ Ak, const ushort_t* __restrict__ Av,
    const ushort_t* __restrict__ Bq, const ushort_t* __restrict__ Bk, const ushort_t* __restrict__ Bv,
    const float* __restrict__ bq, const float* __restrict__ bk, const float* __restrict__ bv,
    ushort_t* __restrict__ Cq, ushort_t* __restrict__ Ck, ushort_t* __restrict__ Vt,
    const float* __restrict__ tmaxbuf) {
  const int K = 1024, N = 1024;
  const int z = blockIdx.z;
  const ushort_t* A = z == 0 ? Aq : z == 1 ? Ak : Av;
  const ushort_t* Bt = z == 0 ? Bq : z == 1 ? Bk : Bv;
  const float* bias = z == 0 ? bq : z == 1 ? bk : bv;

  __shared__ __align__(16) char smem[49152];   // 3 bufs x (A 8KB | B 8KB); 3 blocks/CU
  const int t = threadIdx.x, w = t >> 6, l = t & 63;

  // m-chunk-per-XCD: xcd owns m-blocks [8*xcd, 8*xcd+8), n varies slow
  const int orig = blockIdx.x + gridDim.x * blockIdx.y;   // 0..511
  const int xcd = orig & 7, i = orig >> 3;                // i in 0..63
  const int m0 = (xcd * 8 + (i & 7)) * 128;
  const int n0 = (i >> 3) * 128;
  const int wr = (w >> 1) * 64, wc = (w & 1) * 64;

  if (z != 0) {
    // K/V: rows [m0, m0+128) = tiles tile0, tile0+1 of batch m0>>11
    int b_ = m0 >> 11, tile0 = (m0 & 2047) >> 6;
    unsigned am = active_mask(tmaxbuf + b_ * 32);
    if (!((am >> tile0) & 3u)) return;
  }

  f32x4 acc[4][4] = {};

  const int br0 = 16 * w + (l >> 2);                     // staged row (call 0)
  const int bcs = ((l & 3) ^ ((l >> 3) & 3)) << 3;       // inverse-swizzled ushort col
  const ushort_t* Ab = A + (long)m0 * K;
  const ushort_t* Bb = Bt + (long)n0 * K;

  auto stage = [&](int kk, int buf) {
    char* base = smem + buf * 16384;
    gl_lds16(Ab + (long)br0 * K + kk + bcs, base + w * 1024);
    gl_lds16(Ab + (long)(br0 + 64) * K + kk + bcs, base + 4096 + w * 1024);
    gl_lds16(Bb + (long)br0 * K + kk + bcs, base + 8192 + w * 1024);
    gl_lds16(Bb + (long)(br0 + 64) * K + kk + bcs, base + 12288 + w * 1024);
  };

  stage(0, 0);
  stage(32, 1);

  // fragment-read byte offsets (swizzled chunk)
  const int fsw = ((l >> 4) ^ ((l >> 1) & 3)) << 4;
  const int arow = (wr + (l & 15)) * 64 + fsw;           // A: + m*1024 per m
  const int brow = 8192 + (wc + (l & 15)) * 64 + fsw;    // B: + n*1024 per n

  asm volatile("s_waitcnt vmcnt(4)");                    // stage(0) landed
  __builtin_amdgcn_sched_barrier(0);
  __builtin_amdgcn_s_barrier();

  for (int ts = 0; ts < 32; ts++) {
    const char* base = smem + (ts % 3) * 16384;
    if (ts + 2 < 32) stage((ts + 2) * 32, (ts + 2) % 3); // overwrites buf read at ts-1
    short8 af[4], bfr[4];
#pragma unroll
    for (int m = 0; m < 4; m++)
      af[m] = *(const short8*)(base + arow + m * 1024);
#pragma unroll
    for (int n = 0; n < 4; n++)
      bfr[n] = *(const short8*)(base + brow + n * 1024);
    __builtin_amdgcn_s_setprio(1);
#pragma unroll
    for (int m = 0; m < 4; m++)
#pragma unroll
      for (int n = 0; n < 4; n++)
        acc[m][n] = __builtin_amdgcn_mfma_f32_16x16x32_bf16(af[m], bfr[n], acc[m][n], 0, 0, 0);
    __builtin_amdgcn_s_setprio(0);
    // counted wait: everything except the 4 newest loads (= stage ts+2) has landed,
    // so stage(ts+1) is complete. Never drains the pipeline to 0 mid-loop.
    if (ts < 30) asm volatile("s_waitcnt vmcnt(4)");
    else if (ts == 30) asm volatile("s_waitcnt vmcnt(0)");
    if (ts < 31) {
      __builtin_amdgcn_sched_barrier(0);
      __builtin_amdgcn_s_barrier();
    }
  }
  __builtin_amdgcn_s_barrier();

  // ---- epilogue via per-wave LDS transpose (8 KB/wave; in-wave DS order) ----
  char* Lw = smem + w * 8192;
  if (z != 2) {
#pragma unroll
    for (int nn = 0; nn < 4; nn++) {
      float bvv = bias[n0 + wc + nn * 16 + (l & 15)];
      int dl = nn * 16 + (l & 15);
#pragma unroll
      for (int mm = 0; mm < 4; mm++)
#pragma unroll
        for (int i2 = 0; i2 < 4; i2++) {
          int sl = mm * 16 + (l >> 4) * 4 + i2;
          *(ushort_t*)(Lw + sl * 128 + ((dl * 2) ^ ((sl & 7) << 4))) =
              f2bf(acc[mm][nn][i2] + bvv);
        }
    }
    ushort_t* C = (z == 0 ? Cq : Ck) + (long)(m0 + wr) * N + n0 + wc;
#pragma unroll
    for (int rr = 0; rr < 8; rr++) {
      int sl = rr * 8 + (l >> 3);
      short8 vv = *(const short8*)(Lw + sl * 128 + (((l & 7) * 16) ^ ((sl & 7) << 4)));
      *(short8*)(C + (long)sl * N + (l & 7) * 8) = vv;
    }
  } else {
#pragma unroll
    for (int nn = 0; nn < 4; nn++) {
      float bvv = bias[n0 + wc + nn * 16 + (l & 15)];
      int dl = nn * 16 + (l & 15);
#pragma unroll
      for (int mm = 0; mm < 4; mm++) {
        int sl = mm * 16 + (l >> 4) * 4;
        uint2s pk;
        pk.x = cvt_pk_bf16(acc[mm][nn][0] + bvv, acc[mm][nn][1] + bvv);
        pk.y = cvt_pk_bf16(acc[mm][nn][2] + bvv, acc[mm][nn][3] + bvv);
        *(uint2s*)(Lw + dl * 128 + ((sl * 2) ^ ((dl & 7) << 4))) = pk;
      }
    }
    const int b_ = m0 >> 11;
    const int s0g = (m0 & 2047) + wr;
#pragma unroll
    for (int rr = 0; rr < 8; rr++) {
      int dl = rr * 8 + (l >> 3);
      short8 vv = *(const short8*)(Lw + dl * 128 + (((l & 7) * 16) ^ ((dl & 7) << 4)));
      int dg = n0 + wc + dl;
      long rowbase = ((long)(b_ * 16 + (dg >> 6)) * 64 + (dg & 63)) * 2048;
      *(short8*)(Vt + rowbase + s0g + (l & 7) * 8) = vv;
    }
  }
}

// ---------------- output projection GEMM (bf16 A, f32 out, 3-buf counted-vmcnt) ----------------
__global__ void gemm_o(const ushort_t* __restrict__ A, const ushort_t* __restrict__ Bt,
                       const float* __restrict__ bias, float* __restrict__ C) {
  const int K = 1024, N = 1024;
  __shared__ __align__(16) char smem[49152];   // 3 bufs x (A 8KB | B 8KB)
  const int t = threadIdx.x, w = t >> 6, l = t & 63;

  const int orig = blockIdx.x + gridDim.x * blockIdx.y;   // 0..511
  const int xcd = orig & 7, i = orig >> 3;                // i in 0..63
  const int m0 = (xcd * 8 + (i & 7)) * 128;
  const int n0 = (i >> 3) * 128;
  const int wr = (w >> 1) * 64, wc = (w & 1) * 64;

  f32x4 acc[4][4] = {};

  const int br0 = 16 * w + (l >> 2);
  const int bcs = ((l & 3) ^ ((l >> 3) & 3)) << 3;
  const ushort_t* Ab = A + (long)m0 * K;
  const ushort_t* Bb = Bt + (long)n0 * K;

  auto stage = [&](int kk, int buf) {
    char* base = smem + buf * 16384;
    gl_lds16(Ab + (long)br0 * K + kk + bcs, base + w * 1024);
    gl_lds16(Ab + (long)(br0 + 64) * K + kk + bcs, base + 4096 + w * 1024);
    gl_lds16(Bb + (long)br0 * K + kk + bcs, base + 8192 + w * 1024);
    gl_lds16(Bb + (long)(br0 + 64) * K + kk + bcs, base + 12288 + w * 1024);
  };

  stage(0, 0);
  stage(32, 1);

  const int fsw = ((l >> 4) ^ ((l >> 1) & 3)) << 4;
  const int arow = (wr + (l & 15)) * 64 + fsw;
  const int brow = 8192 + (wc + (l & 15)) * 64 + fsw;

  asm volatile("s_waitcnt vmcnt(4)");
  __builtin_amdgcn_sched_barrier(0);
  __builtin_amdgcn_s_barrier();

  for (int ts = 0; ts < 32; ts++) {
    const char* base = smem + (ts % 3) * 16384;
    if (ts + 2 < 32) stage((ts + 2) * 32, (ts + 2) % 3);
    short8 af[4], bfr[4];
#pragma unroll
    for (int m = 0; m < 4; m++)
      af[m] = *(const short8*)(base + arow + m * 1024);
#pragma unroll
    for (int n = 0; n < 4; n++)
      bfr[n] = *(const short8*)(base + brow + n * 1024);
    __builtin_amdgcn_s_setprio(1);
#pragma unroll
    for (int m = 0; m < 4; m++)
#pragma unroll
      for (int n = 0; n < 4; n++)
        acc[m][n] = __builtin_amdgcn_mfma_f32_16x16x32_bf16(af[m], bfr[n], acc[m][n], 0, 0, 0);
    __builtin_amdgcn_s_setprio(0);
    if (ts < 30) asm volatile("s_waitcnt vmcnt(4)");
    else if (ts == 30) asm volatile("s_waitcnt vmcnt(0)");
    if (ts < 31) {
      __builtin_amdgcn_sched_barrier(0);
      __builtin_amdgcn_s_barrier();
    }
  }

#pragma unroll
  for (int mm = 0; mm < 4; mm++)
#pragma unroll
    for (int nn = 0; nn < 4; nn++) {
      int c = n0 + wc + nn * 16 + (l & 15);
      float bv = bias[c];
#pragma unroll
      for (int i2 = 0; i2 < 4; i2++) {
        int r = m0 + wr + mm * 16 + (l >> 4) * 4 + i2;
        C[(long)r * N + c] = acc[mm][nn][i2] + bv;
      }
    }
}

// ---------------- flash attention (swapped 32x32, block-sparse via mask tile-max) ----------------
__global__ __launch_bounds__(256, 4) void attn(
    const ushort_t* __restrict__ Qp, const ushort_t* __restrict__ Kp,
    const ushort_t* __restrict__ Vt, const float* __restrict__ maskpre,
    const float* __restrict__ tmaxbuf, ushort_t* __restrict__ Ob) {
  const int S = 2048, DM = 1024;
  __shared__ __align__(16) char smem[32768];
  char* KlB = smem;                 // 2 x 8192
  char* VlB = smem + 16384;         // 2 x 8192

  const int t = threadIdx.x, w = t >> 6, l = t & 63;
  const int lq = l & 31, hi = l >> 5;
  const int hib = hi * 16;

  const int orig = blockIdx.x + (blockIdx.y << 4) + (blockIdx.z << 8);
  const int work = ((orig & 7) << 7) + (orig >> 3);
  const int qx = work & 15;
  const int hb = work >> 4;          // [0,64)
  const int h = hb & 15, b = hb >> 4;
  const int q0w = qx * 128 + w * 32;

  const float C1 = 0.1803368801f;      // 0.125 * log2(e)

  const ushort_t* Kbase = Kp + (long)(b * S) * DM + h * 64;
  const ushort_t* Vbase = Vt + (long)((b * 16 + h) * 64) * S;
  const float* Mbase = maskpre + (long)b * S;

  short8 qB[4];
  {
    const ushort_t* Qb = Qp + ((long)(b * S) + q0w + lq) * DM + h * 64;
#pragma unroll
    for (int kh = 0; kh < 4; kh++)
      qB[kh] = *(const short8*)(Qb + kh * 16 + hi * 8);
  }

  const int so0 = w * 2048 + l * 16;
  const int sr0 = so0 >> 7, sc0 = (so0 & 127) ^ ((sr0 & 7) << 4);
  const int so1 = so0 + 1024;
  const int sr1 = so1 >> 7, sc1 = (so1 & 127) ^ ((sr1 & 7) << 4);
  const ushort_t* Kg0 = Kbase + (long)sr0 * DM + (sc0 >> 1);
  const ushort_t* Kg1 = Kbase + (long)sr1 * DM + (sc1 >> 1);
  const ushort_t* Vg0 = Vbase + (long)sr0 * S + (sc0 >> 1);
  const ushort_t* Vg1 = Vbase + (long)sr1 * S + (sc1 >> 1);
  char* Kd0 = KlB + w * 2048;
  char* Vd0 = VlB + w * 2048;

  auto stage = [&](int kv0, int bb) {
    long ko = (long)kv0 * DM;
    int bo = bb * 8192;
    gl_lds16(Kg0 + ko, Kd0 + bo);
    gl_lds16(Kg1 + ko, Kd0 + bo + 1024);
    gl_lds16(Vg0 + kv0, Vd0 + bo);
    gl_lds16(Vg1 + kv0, Vd0 + bo + 1024);
  };

  unsigned amask = active_mask(tmaxbuf + b * 32);

  int cur = (int)__builtin_ctz(amask);   // bit 0 always set
  stage(cur * 64, 0);
  __syncthreads();

  const int lbase = lq * 128 + ((lq & 7) << 4);   // row lq base ^ swizzle (bytes)

  f32x16 o0 = {}, o1 = {};           // O^T: row d (0..31 / 32..63), col q=lq
  float mrun = -INFINITY, lsum = 0.f;
  int bb = 0;

  while (cur >= 0) {
    unsigned rem = amask & (0xFFFFFFFEu << cur);
    int nxt = rem ? (int)__builtin_ctz(rem) : -1;
    if (nxt >= 0) stage(nxt * 64, bb ^ 1);
    const int bx = lbase + (bb << 13);
    const int kv0 = cur * 64;

    f32x16 s0 = {}, s1 = {};
    __builtin_amdgcn_s_setprio(1);
#pragma unroll
    for (int kh = 0; kh < 4; kh++) {
      int a = bx ^ (kh * 32 + hib);
      short8 ka0 = *(const short8*)(KlB + a);
      short8 ka1 = *(const short8*)(KlB + a + 4096);
      s0 = __builtin_amdgcn_mfma_f32_32x32x16_bf16(ka0, qB[kh], s0, 0, 0, 0);
      s1 = __builtin_amdgcn_mfma_f32_32x32x16_bf16(ka1, qB[kh], s1, 0, 0, 0);
    }
    __builtin_amdgcn_s_setprio(0);

    const float* mq = Mbase + kv0;
#pragma unroll
    for (int g = 0; g < 4; g++) {
      f32x4 m0 = *(const f32x4*)(mq + g * 8 + hi * 4);
      f32x4 m1 = *(const f32x4*)(mq + 32 + g * 8 + hi * 4);
#pragma unroll
      for (int c = 0; c < 4; c++) {
        s0[g * 4 + c] = fmaf(s0[g * 4 + c], C1, m0[c]);
        s1[g * 4 + c] = fmaf(s1[g * 4 + c], C1, m1[c]);
      }
    }

    float mx0 = -INFINITY, mx1 = -INFINITY, mx2 = -INFINITY, mx3 = -INFINITY;
#pragma unroll
    for (int r = 0; r < 4; r++) {
      mx0 = fmaxf(mx0, fmaxf(s0[r], s0[r + 4]));
      mx1 = fmaxf(mx1, fmaxf(s0[r + 8], s0[r + 12]));
      mx2 = fmaxf(mx2, fmaxf(s1[r], s1[r + 4]));
      mx3 = fmaxf(mx3, fmaxf(s1[r + 8], s1[r + 12]));
    }
    float mx = fmaxf(fmaxf(mx0, mx1), fmaxf(mx2, mx3));
    mx = fmaxf(mx, __shfl_xor(mx, 32));

    if (!__all((int)(mx <= mrun + 8.f))) {
      float mnew = fmaxf(mrun, mx);
      float sc = __builtin_amdgcn_exp2f(mrun - mnew);
      mrun = mnew;
      lsum *= sc;
#pragma unroll
      for (int r = 0; r < 16; r++) { o0[r] *= sc; o1[r] *= sc; }
    }

    float ps0 = 0.f, ps1 = 0.f, ps2 = 0.f, ps3 = 0.f;
#pragma unroll
    for (int r = 0; r < 8; r++) {
      float p0 = __builtin_amdgcn_exp2f(s0[r] - mrun);
      float p1 = __builtin_amdgcn_exp2f(s0[r + 8] - mrun);
      float p2 = __builtin_amdgcn_exp2f(s1[r] - mrun);
      float p3 = __builtin_amdgcn_exp2f(s1[r + 8] - mrun);
      s0[r] = p0; s0[r + 8] = p1; s1[r] = p2; s1[r + 8] = p3;
      ps0 += p0; ps1 += p1; ps2 += p2; ps3 += p3;
    }
    float ps = (ps0 + ps1) + (ps2 + ps3);
    ps += __shfl_xor(ps, 32);
    lsum += ps;

    // ---- PV: P repacked in-register via v_cvt_pk + permlane32_swap (T12) ----
#pragma unroll
    for (int half = 0; half < 2; half++) {
      const f32x16& sv = half ? s1 : s0;
      unsigned x0 = cvt_pk_bf16(sv[0], sv[1]);
      unsigned z0 = cvt_pk_bf16(sv[2], sv[3]);
      unsigned y0 = cvt_pk_bf16(sv[4], sv[5]);
      unsigned u0 = cvt_pk_bf16(sv[6], sv[7]);
      unsigned x1 = cvt_pk_bf16(sv[8], sv[9]);
      unsigned z1 = cvt_pk_bf16(sv[10], sv[11]);
      unsigned y1 = cvt_pk_bf16(sv[12], sv[13]);
      unsigned u1 = cvt_pk_bf16(sv[14], sv[15]);
      uint2v a1 = __builtin_amdgcn_permlane32_swap(x0, y0, false, false);
      uint2v a2 = __builtin_amdgcn_permlane32_swap(z0, u0, false, false);
      uint2v a3 = __builtin_amdgcn_permlane32_swap(x1, y1, false, false);
      uint2v a4 = __builtin_amdgcn_permlane32_swap(z1, u1, false, false);
      uint4v f0, f1;
      f0.x = a1.x; f0.y = a2.x; f0.z = a1.y; f0.w = a2.y;
      f1.x = a3.x; f1.y = a4.x; f1.z = a3.y; f1.w = a4.y;
      short8 pB0 = __builtin_bit_cast(short8, f0);
      short8 pB1 = __builtin_bit_cast(short8, f1);
      __builtin_amdgcn_s_setprio(1);
#pragma unroll
      for (int kt2 = 0; kt2 < 2; kt2++) {
        short8 pB = kt2 ? pB1 : pB0;
        int a = bx ^ (half * 64 + kt2 * 32 + hib);
        short8 va0 = *(const short8*)(VlB + a);
        short8 va1 = *(const short8*)(VlB + a + 4096);
        o0 = __builtin_amdgcn_mfma_f32_32x32x16_bf16(va0, pB, o0, 0, 0, 0);
        o1 = __builtin_amdgcn_mfma_f32_32x32x16_bf16(va1, pB, o1, 0, 0, 0);
      }
      __builtin_amdgcn_s_setprio(0);
    }
    __syncthreads();
    bb ^= 1;
    cur = nxt;
  }

  __syncthreads();
  char* Ow = smem + w * 4096;        // [32 q][64 d] bf16, XOR-swizzled rows
  float inv = 1.0f / lsum;
#pragma unroll
  for (int r = 0; r < 16; r++) {
    int d0 = (r & 3) + 8 * (r >> 2) + 4 * hi;
    int a0 = lq * 128 + ((d0 * 2) ^ ((lq & 7) << 4));
    *(ushort_t*)(Ow + a0) = f2bf(o0[r] * inv);
    int d1 = 32 + d0;
    int a1 = lq * 128 + ((d1 * 2) ^ ((lq & 7) << 4));
    *(ushort_t*)(Ow + a1) = f2bf(o1[r] * inv);
  }
  ushort_t* Obase = Ob + ((long)(b * S) + q0w) * DM + h * 64;
#pragma unroll
  for (int rr = 0; rr < 4; rr++) {
    int q = rr * 8 + (l >> 3);
    int a = q * 128 + (((l & 7) * 16) ^ ((q & 7) << 4));
    short8 vv = *(const short8*)(Ow + a);
    *(short8*)(Obase + (long)q * DM + (l & 7) * 8) = vv;
  }
}

// ---------------- launch ----------------
extern "C" void kernel_launch(void* const* d_in, const int* in_sizes, int n_in,
                              void* d_out, int out_size, void* d_ws, size_t ws_size,
                              hipStream_t stream) {
  const float* query = (const float*)d_in[0];
  const float* key   = (const float*)d_in[1];
  const float* value = (const float*)d_in[2];
  const float* mask  = (const float*)d_in[3];
  const float* Wq = (const float*)d_in[4];
  const float* bq = (const float*)d_in[5];
  const float* Wk = (const float*)d_in[6];
  const float* bk = (const float*)d_in[7];
  const float* Wv = (const float*)d_in[8];
  const float* bv = (const float*)d_in[9];
  const float* Wo = (const float*)d_in[10];
  const float* bo = (const float*)d_in[11];

  const int B = 4, S = 2048, DM = 1024, H = 16;
  const long M = (long)B * S;            // 8192
  const long XB = (long)1 << 24;         // 16 MiB bf16 activation bytes

  char* ws = (char*)d_ws;
  ushort_t* Wqt = (ushort_t*)(ws);
  ushort_t* Wkt = (ushort_t*)(ws + (1l << 21));
  ushort_t* Wvt = (ushort_t*)(ws + 2 * (1l << 21));
  ushort_t* Wot = (ushort_t*)(ws + 3 * (1l << 21));
  ushort_t* Xv  = (ushort_t*)(ws + 4 * (1l << 21));
  ushort_t* Qp  = (ushort_t*)(ws + 4 * (1l << 21) + XB);
  ushort_t* Kp  = Qp + M * DM;
  ushort_t* Vtr = Kp + M * DM;           // Vt[B,H,64,S] (Vp never materialized)
  float* maskpre = (float*)(Vtr + M * DM);
  float* tmaxbuf = maskpre + (long)B * S;
  ushort_t* AO  = Xv;                    // Xv dead after V projection
  ushort_t* Xq  = (ushort_t*)d_out;      // d_out holds 2 bf16 scratch arrays
  ushort_t* Xk  = Xq + M * DM;

  prep0<<<9, 256, 0, stream>>>(mask, maskpre, tmaxbuf);

  prep1<<<7168, 256, 0, stream>>>((const float4*)query, (const float4*)key,
                                  (const float4*)value, (ushort4*)Xq, (ushort4*)Xk,
                                  (ushort4*)Xv, Wq, Wk, Wv, Wo, Wqt, Wkt, Wvt, Wot,
                                  tmaxbuf);

  gemm_qkv3<<<dim3(64, 8, 3), 256, 0, stream>>>(Xq, Xk, Xv, Wqt, Wkt, Wvt,
                                                bq, bk, bv, Qp, Kp, Vtr, tmaxbuf);

  attn<<<dim3(16, 16, 4), 256, 0, stream>>>(Qp, Kp, Vtr, maskpre, tmaxbuf, AO);

  gemm_o<<<dim3(64, 8), 256, 0, stream>>>(AO, Wot, bo, (float*)d_out);
}